// Round 4
// baseline (256.890 us; speedup 1.0000x reference)
//
#include <hip/hip_runtime.h>
#include <hip/hip_fp16.h>

#define OUT_DIM 128
#define NPS 256              // nodes per super-bucket (scatter1 binning)
#define NS_MAX 400           // supers per matrix (391 actual)
#define CAP_S 4608           // payload slots per super (mean 4096 + 8 sigma)
#define HNPS 128             // nodes per half-super (fused kernels)
#define CAPH 2560            // LDS slots per half-super (mean 2048 + 11 sigma)
#define EPTF 18              // CAP_S / 256
#define SBLK1 256
#define EPT1 16
#define CHUNK1 (SBLK1 * EPT1)   // 4096
#define GBLK 256

// ---------- pass 1: chunk-local counting sort + coalesced run write-out ----------
// UNCHANGED from round 3.
__global__ __launch_bounds__(SBLK1) void scatter1_kernel(
    const int* __restrict__ adj_rows, const int* __restrict__ adj_cols,
    const float* __restrict__ adj_vals, int nnz_a, int nCkA,
    const int* __restrict__ feat_rows, const int* __restrict__ feat_cols,
    const float* __restrict__ feat_vals, int nnz_x,
    int* __restrict__ cur, int2* __restrict__ pay, int ns)
{
    __shared__ int2 s_stage[CHUNK1];            // 32 KB, chunk sorted by super
    __shared__ unsigned short s_bin[CHUNK1];    // 8 KB, bin of each staged slot
    __shared__ int s_hist[NS_MAX];              // counts -> rank cursor
    __shared__ int s_excl[NS_MAX];              // chunk-local exclusive offsets
    __shared__ int s_gbase[NS_MAX];             // global run base within super

    int tid = threadIdx.x;
    bool isA = ((int)blockIdx.x < nCkA);
    const int* rows; const int* cols; const float* vals;
    int nnz, start, matbase;
    if (isA) {
        rows = adj_rows; cols = adj_cols; vals = adj_vals; nnz = nnz_a;
        start = (int)blockIdx.x * CHUNK1; matbase = 0;
    } else {
        rows = feat_rows; cols = feat_cols; vals = feat_vals; nnz = nnz_x;
        start = ((int)blockIdx.x - nCkA) * CHUNK1; matbase = ns;
    }
    int total = nnz - start; if (total > CHUNK1) total = CHUNK1;

    for (int i = tid; i < ns; i += SBLK1) s_hist[i] = 0;
    __syncthreads();

    int rr[EPT1]; int cc[EPT1]; float vv[EPT1];
    #pragma unroll
    for (int k = 0; k < EPT1; ++k) {
        int e = start + k * SBLK1 + tid;
        rr[k] = -1;
        if (e < nnz) {
            rr[k] = rows[e]; cc[k] = cols[e]; vv[k] = vals[e];
            atomicAdd(&s_hist[rr[k] >> 8], 1);
        }
    }
    __syncthreads();

    // wave 0: exclusive scan of s_hist[0..ns) -> s_excl
    if (tid < 64) {
        int carry = 0;
        for (int seg = 0; seg < ns; seg += 64) {
            int idx = seg + tid;
            int x = (idx < ns) ? s_hist[idx] : 0;
            int incl = x;
            #pragma unroll
            for (int off = 1; off < 64; off <<= 1) {
                int y = __shfl_up(incl, off, 64);
                if (tid >= off) incl += y;
            }
            if (idx < ns) s_excl[idx] = carry + incl - x;
            carry += __shfl(incl, 63, 64);
        }
    }
    __syncthreads();

    // reserve global runs (one atomic per non-empty super)
    for (int i = tid; i < ns; i += SBLK1) {
        int c = s_hist[i];
        s_gbase[i] = (c > 0) ? atomicAdd(&cur[matbase + i], c) : 0;
        s_hist[i] = 0;   // reuse as rank cursor
    }
    __syncthreads();

    // scatter into sorted LDS staging
    #pragma unroll
    for (int k = 0; k < EPT1; ++k) {
        if (rr[k] >= 0) {
            int b = rr[k] >> 8;
            int rl = rr[k] & 255;
            int pos = s_excl[b] + atomicAdd(&s_hist[b], 1);
            s_stage[pos] = make_int2((rl << 17) | cc[k], __float_as_int(vv[k]));
            s_bin[pos] = (unsigned short)b;
        }
    }
    __syncthreads();

    // coalesced write-out: consecutive threads -> consecutive slots of a run
    for (int i = tid; i < total; i += SBLK1) {
        int b = s_bin[i];
        int g = s_gbase[b] + (i - s_excl[b]);
        if (g < CAP_S)
            pay[(size_t)(matbase + b) * CAP_S + g] = s_stage[i];
    }
}

// ---------- cast W to fp16 ----------
__global__ void wcast_kernel(const float* __restrict__ W, __half* __restrict__ W16, int n) {
    int i = blockIdx.x * blockDim.x + threadIdx.x;
    if (i < n) W16[i] = __float2half(W[i]);
}

// ---------- fused stage 1: in-LDS node-sort of one half-super + XW gather ----------
// Replaces {sort2 + gather_xw}: no global payload round-trip, no row_span.
// Block = half-super (128 nodes). 21.5 KB LDS -> 4 blocks/CU possible;
// grid 782 x 4 waves = 12.2 waves/CU.
__global__ __launch_bounds__(GBLK, 4) void fused_xw_kernel(
    const int* __restrict__ cur, const int2* __restrict__ pay,
    const __half* __restrict__ W16, __half* __restrict__ XW,
    int ns, int n_nodes)
{
    __shared__ int2 s_edge[CAPH];     // 20 KB sorted payload for this half
    __shared__ int s_cnt[HNPS];
    __shared__ int s_excl[HNPS];
    int tid = threadIdx.x;
    int sb = blockIdx.x >> 1;         // super index
    int h  = blockIdx.x & 1;          // which half (rl bit 7)
    int count = cur[ns + sb]; if (count > CAP_S) count = CAP_S;
    const int2* region = pay + (size_t)(ns + sb) * CAP_S;

    if (tid < HNPS) s_cnt[tid] = 0;
    __syncthreads();

    // stage full super bucket in registers, keep this half's entries
    int2 er[EPTF];
    #pragma unroll
    for (int k = 0; k < EPTF; ++k) {
        int i = tid + k * GBLK;
        er[k] = make_int2(-1, 0);
        if (i < count) {
            int2 e = region[i];
            int rl = ((unsigned)e.x) >> 17;
            if ((rl >> 7) == h) {
                er[k] = e;
                atomicAdd(&s_cnt[rl & (HNPS - 1)], 1);
            }
        }
    }
    __syncthreads();

    // wave 0: exclusive scan of s_cnt[0..128) -> s_excl
    if (tid < 64) {
        int carry = 0;
        #pragma unroll
        for (int seg = 0; seg < HNPS; seg += 64) {
            int x = s_cnt[seg + tid];
            int incl = x;
            #pragma unroll
            for (int off = 1; off < 64; off <<= 1) {
                int y = __shfl_up(incl, off, 64);
                if (tid >= off) incl += y;
            }
            s_excl[seg + tid] = carry + incl - x;
            carry += __shfl(incl, 63, 64);
        }
    }
    __syncthreads();

    // rank-scatter into sorted LDS buffer
    #pragma unroll
    for (int k = 0; k < EPTF; ++k) {
        if (er[k].x >= 0) {
            int rl = (((unsigned)er[k].x) >> 17) & (HNPS - 1);
            int pos = atomicAdd(&s_excl[rl], 1);
            if (pos < CAPH) s_edge[pos] = er[k];
        }
    }
    __syncthreads();

    // gather phase: 16 lane-groups x 8 nodes each; every node row written
    // (cnt==0 -> zero row, required: XW is uninitialized workspace).
    int lane = tid & 15;
    int grp = tid >> 4;
    const int4* Wv = (const int4*)W16;          // row = 16 int4 (8 halves each)
    for (int r = grp; r < HNPS; r += 16) {
        int node = sb * NPS + h * HNPS + r;
        if (node >= n_nodes) break;             // uniform per group
        int cnt = s_cnt[r];
        int start = s_excl[r] - cnt;            // post-scatter cursor = end
        float a0=0,a1=0,a2=0,a3=0,a4=0,a5=0,a6=0,a7=0;
        for (int base = 0; base < cnt; base += 16) {
            int2 pl = make_int2(0, 0);
            if (base + lane < cnt) pl = s_edge[start + base + lane];
            int4 w[16];
            #pragma unroll
            for (int j = 0; j < 16; ++j) {
                int c = __shfl(pl.x, j, 16) & 0x1FFFF;  // pad lanes: c=0, v=0
                w[j] = Wv[(c << 4) | lane];
            }
            #pragma unroll
            for (int j = 0; j < 16; ++j) {
                float v = __int_as_float(__shfl(pl.y, j, 16));
                union { int4 i4; __half2 hh[4]; } u;
                u.i4 = w[j];
                float2 f0 = __half22float2(u.hh[0]);
                float2 f1 = __half22float2(u.hh[1]);
                float2 f2 = __half22float2(u.hh[2]);
                float2 f3 = __half22float2(u.hh[3]);
                a0 += v * f0.x; a1 += v * f0.y; a2 += v * f1.x; a3 += v * f1.y;
                a4 += v * f2.x; a5 += v * f2.y; a6 += v * f3.x; a7 += v * f3.y;
            }
        }
        union { int4 i4; __half2 hh[4]; } o;
        o.hh[0] = __floats2half2_rn(a0, a1);
        o.hh[1] = __floats2half2_rn(a2, a3);
        o.hh[2] = __floats2half2_rn(a4, a5);
        o.hh[3] = __floats2half2_rn(a6, a7);
        ((int4*)(XW + (size_t)node * OUT_DIM))[lane] = o.i4;
    }
}

// ---------- fused stage 2: in-LDS node-sort of one half-super + AGG gather ----------
// Gather inner loop is the frozen round-2 form (w[16] batch, pad-to-16),
// sourced from LDS; the random XW gather pattern and TLP (~12 waves/CU) match
// the frozen kernel's measured 4 TB/s operating point.
__global__ __launch_bounds__(GBLK, 4) void fused_agg_kernel(
    const int* __restrict__ cur, const int2* __restrict__ pay,
    const __half* __restrict__ XW, float* __restrict__ out,
    int ns, int n_nodes)
{
    __shared__ int2 s_edge[CAPH];
    __shared__ int s_cnt[HNPS];
    __shared__ int s_excl[HNPS];
    int tid = threadIdx.x;
    int sb = blockIdx.x >> 1;
    int h  = blockIdx.x & 1;
    int count = cur[sb]; if (count > CAP_S) count = CAP_S;
    const int2* region = pay + (size_t)sb * CAP_S;

    if (tid < HNPS) s_cnt[tid] = 0;
    __syncthreads();

    int2 er[EPTF];
    #pragma unroll
    for (int k = 0; k < EPTF; ++k) {
        int i = tid + k * GBLK;
        er[k] = make_int2(-1, 0);
        if (i < count) {
            int2 e = region[i];
            int rl = ((unsigned)e.x) >> 17;
            if ((rl >> 7) == h) {
                er[k] = e;
                atomicAdd(&s_cnt[rl & (HNPS - 1)], 1);
            }
        }
    }
    __syncthreads();

    if (tid < 64) {
        int carry = 0;
        #pragma unroll
        for (int seg = 0; seg < HNPS; seg += 64) {
            int x = s_cnt[seg + tid];
            int incl = x;
            #pragma unroll
            for (int off = 1; off < 64; off <<= 1) {
                int y = __shfl_up(incl, off, 64);
                if (tid >= off) incl += y;
            }
            s_excl[seg + tid] = carry + incl - x;
            carry += __shfl(incl, 63, 64);
        }
    }
    __syncthreads();

    #pragma unroll
    for (int k = 0; k < EPTF; ++k) {
        if (er[k].x >= 0) {
            int rl = (((unsigned)er[k].x) >> 17) & (HNPS - 1);
            int pos = atomicAdd(&s_excl[rl], 1);
            if (pos < CAPH) s_edge[pos] = er[k];
        }
    }
    __syncthreads();

    int lane = tid & 15;
    int grp = tid >> 4;
    const int4* Xv = (const int4*)XW;
    for (int r = grp; r < HNPS; r += 16) {
        int node = sb * NPS + h * HNPS + r;
        if (node >= n_nodes) break;
        int cnt = s_cnt[r];
        int start = s_excl[r] - cnt;
        float a0=0,a1=0,a2=0,a3=0,a4=0,a5=0,a6=0,a7=0;
        for (int base = 0; base < cnt; base += 16) {
            int2 pl = make_int2(0, 0);
            if (base + lane < cnt) pl = s_edge[start + base + lane];
            int4 w[16];
            #pragma unroll
            for (int j = 0; j < 16; ++j) {
                int c = __shfl(pl.x, j, 16) & 0x1FFFF;  // src node; pad: row 0
                w[j] = Xv[(size_t)((c << 4) | lane)];
            }
            #pragma unroll
            for (int j = 0; j < 16; ++j) {
                float v = __int_as_float(__shfl(pl.y, j, 16));  // pad lanes: 0
                union { int4 i4; __half2 hh[4]; } u;
                u.i4 = w[j];
                float2 f0 = __half22float2(u.hh[0]);
                float2 f1 = __half22float2(u.hh[1]);
                float2 f2 = __half22float2(u.hh[2]);
                float2 f3 = __half22float2(u.hh[3]);
                a0 += v * f0.x; a1 += v * f0.y; a2 += v * f1.x; a3 += v * f1.y;
                a4 += v * f2.x; a5 += v * f2.y; a6 += v * f3.x; a7 += v * f3.y;
            }
        }
        float4 lo, hi;
        lo.x = fmaxf(a0, 0.f); lo.y = fmaxf(a1, 0.f);
        lo.z = fmaxf(a2, 0.f); lo.w = fmaxf(a3, 0.f);
        hi.x = fmaxf(a4, 0.f); hi.y = fmaxf(a5, 0.f);
        hi.z = fmaxf(a6, 0.f); hi.w = fmaxf(a7, 0.f);
        float4* orow = (float4*)(out + (size_t)node * OUT_DIM);
        orow[2 * lane]     = lo;
        orow[2 * lane + 1] = hi;
    }
}

extern "C" void kernel_launch(void* const* d_in, const int* in_sizes, int n_in,
                              void* d_out, int out_size, void* d_ws, size_t ws_size,
                              hipStream_t stream) {
    const int*   feat_rows = (const int*)d_in[0];
    const int*   feat_cols = (const int*)d_in[1];
    const float* feat_vals = (const float*)d_in[2];
    const int*   adj_rows  = (const int*)d_in[3];
    const int*   adj_cols  = (const int*)d_in[4];
    const float* adj_vals  = (const float*)d_in[5];
    const float* W         = (const float*)d_in[6];
    float*       out       = (float*)d_out;

    const int nnz_x   = in_sizes[0];
    const int nnz_a   = in_sizes[3];
    const int n_w     = in_sizes[6];          // 256*128
    const int n_nodes = out_size / OUT_DIM;
    const int ns      = (n_nodes + NPS - 1) / NPS;   // 391

    // ---- workspace layout (~54.5 MB) ----
    char* p = (char*)d_ws;
    __half* XW   = (__half*)p;  p += (size_t)n_nodes * OUT_DIM * sizeof(__half); // 25.6 MB
    __half* W16  = (__half*)p;  p += (size_t)n_w * sizeof(__half);               // 64 KB
    p = (char*)(((uintptr_t)p + 15) & ~(uintptr_t)15);
    int2* pay    = (int2*)p;    p += (size_t)2 * ns * CAP_S * sizeof(int2);      // 28.8 MB
    int* cur     = (int*)p;     p += (size_t)2 * ns * sizeof(int);

    hipMemsetAsync(cur, 0, (size_t)2 * ns * sizeof(int), stream);

    wcast_kernel<<<(n_w + 255) / 256, 256, 0, stream>>>(W, W16, n_w);

    const int nCkA = (nnz_a + CHUNK1 - 1) / CHUNK1;
    const int nCkX = (nnz_x + CHUNK1 - 1) / CHUNK1;
    scatter1_kernel<<<nCkA + nCkX, SBLK1, 0, stream>>>(
        adj_rows, adj_cols, adj_vals, nnz_a, nCkA,
        feat_rows, feat_cols, feat_vals, nnz_x,
        cur, pay, ns);

    const int nhb = 2 * ns;     // 782 half-super blocks per matrix
    fused_xw_kernel<<<nhb, GBLK, 0, stream>>>(cur, pay, W16, XW, ns, n_nodes);
    fused_agg_kernel<<<nhb, GBLK, 0, stream>>>(cur, pay, XW, out, ns, n_nodes);
}